// Round 14
// baseline (160.870 us; speedup 1.0000x reference)
//
#include <hip/hip_runtime.h>

// ROI bilinear pooling (TF1 resize_images align_corners=False semantics).
// img: (1, 100, 100, 1024) f32 NHWC ; rois: (1, 512, 4) f32 (int-valued x,y,w,h)
// out: (1, 512, 7, 7, 1024) f32
//
// v5: per-wave MLP probe. 128-thread blocks, 8 ch/thread -> each wave issues
// 8 independent coalesced 1KB loads per position (2 per bilinear corner:
// channel halves c and c+512), vs 4 in v3. No cross-iteration prefetch, so
// in-flight data = 32 VGPR and occupancy stays at the 8-waves/SIMD cap
// (v4's pipeline+pair blew the VGPR budget and was null).
// Keeps XCD-local ROI-major sweep + nontemporal stores.
// Grid: 4096 blocks = 16 blocks/CU = 32 waves/CU.

#define IMG_H 100
#define IMG_W 100
#define IMG_C 1024
#define N_ROI 512
#define POOLP 7
#define NPOS  (N_ROI * POOLP * POOLP)    // 25088
#define NBLK  4096                        // 16 blocks/CU (128 thr) = 32 waves/CU
#define ROI_PER_XCD   (N_ROI / 8)         // 64
#define UNITS_PER_XCD (ROI_PER_XCD * 49)  // 3136
#define BLK_PER_XCD   (NBLK / 8)          // 512

typedef float f32x4 __attribute__((ext_vector_type(4)));

__global__ __launch_bounds__(128) void roi_pool_kernel(
    const float* __restrict__ img,
    const float* __restrict__ rois,
    float* __restrict__ out)
{
    const int b    = blockIdx.x;
    const int xcd  = b & 7;            // heuristic XCD id (round-robin dispatch)
    const int l    = b >> 3;           // local block on this XCD, 0..511
    const int base = xcd * UNITS_PER_XCD;

    // 8 channels per thread, as two coalesced float4 groups: c0 and c0+512
    const int c0 = threadIdx.x << 2;         // 0..508
    const int c1 = c0 + 512;                 // 512..1020

    for (int u = l; u < UNITS_PER_XCD; u += BLK_PER_XCD) {
        const int p   = base + u;
        const int roi = p / 49;
        const int pos = p - roi * 49;
        const int py  = pos / 7;
        const int px  = pos - py * 7;

        const f32x4 rv = *reinterpret_cast<const f32x4*>(rois + roi * 4);
        const int x = (int)rv.x;
        const int y = (int)rv.y;
        const int w = (int)rv.z;
        const int h = (int)rv.w;

        // keep EXACT reference math: s = out_idx * (size / 7.0f), floor
        const float sx  = (float)px * ((float)w / (float)POOLP);
        const int   ix0 = (int)floorf(sx);
        const int   ix1 = min(ix0 + 1, w - 1);
        const float fx  = sx - (float)ix0;
        const int ax0 = min(max(x + ix0, 0), IMG_W - 1);
        const int ax1 = min(max(x + ix1, 0), IMG_W - 1);

        const float sy  = (float)py * ((float)h / (float)POOLP);
        const int   iy0 = (int)floorf(sy);
        const int   iy1 = min(iy0 + 1, h - 1);
        const float fy  = sy - (float)iy0;
        const int ay0 = min(max(y + iy0, 0), IMG_H - 1);
        const int ay1 = min(max(y + iy1, 0), IMG_H - 1);

        const float* b00 = img + (size_t)(ay0 * IMG_W + ax0) * IMG_C;
        const float* b01 = img + (size_t)(ay0 * IMG_W + ax1) * IMG_C;
        const float* b10 = img + (size_t)(ay1 * IMG_W + ax0) * IMG_C;
        const float* b11 = img + (size_t)(ay1 * IMG_W + ax1) * IMG_C;

        // 8 independent loads -> 8 outstanding per wave
        const f32x4 a00 = *reinterpret_cast<const f32x4*>(b00 + c0);
        const f32x4 a01 = *reinterpret_cast<const f32x4*>(b01 + c0);
        const f32x4 a10 = *reinterpret_cast<const f32x4*>(b10 + c0);
        const f32x4 a11 = *reinterpret_cast<const f32x4*>(b11 + c0);
        const f32x4 d00 = *reinterpret_cast<const f32x4*>(b00 + c1);
        const f32x4 d01 = *reinterpret_cast<const f32x4*>(b01 + c1);
        const f32x4 d10 = *reinterpret_cast<const f32x4*>(b10 + c1);
        const f32x4 d11 = *reinterpret_cast<const f32x4*>(b11 + c1);

        const float gx = 1.0f - fx;
        const float gy = 1.0f - fy;

        f32x4 topA = a00 * gx + a01 * fx;
        f32x4 botA = a10 * gx + a11 * fx;
        f32x4 oA   = topA * gy + botA * fy;

        f32x4 topD = d00 * gx + d01 * fx;
        f32x4 botD = d10 * gx + d11 * fx;
        f32x4 oD   = topD * gy + botD * fy;

        float* ob = out + (size_t)p * IMG_C;
        __builtin_nontemporal_store(oA, reinterpret_cast<f32x4*>(ob + c0));
        __builtin_nontemporal_store(oD, reinterpret_cast<f32x4*>(ob + c1));
    }
}

extern "C" void kernel_launch(void* const* d_in, const int* in_sizes, int n_in,
                              void* d_out, int out_size, void* d_ws, size_t ws_size,
                              hipStream_t stream)
{
    const float* img  = (const float*)d_in[0];
    const float* rois = (const float*)d_in[1];
    float* out = (float*)d_out;

    roi_pool_kernel<<<NBLK, 128, 0, stream>>>(img, rois, out);
}